// Round 5
// baseline (233.212 us; speedup 1.0000x reference)
//
#include <hip/hip_runtime.h>
#include <math.h>

// NoisyTopkRouter round 5: bf16x2-split MFMA, K=64 per barrier stage.
// - A: fp32 -> hi/lo bf16 once per block into double-buffered LDS; raw-A
//   register pipeline depth 3 STAGES (slack ~2 iterations > HBM latency).
// - B: prepacked frag-order planes (L1/L2-resident), loaded at stage top,
//   consumed after the convert-VALU block (fills L2 latency window).
// - Wave w: route ntile w + noise ntile w+4 -> lane-local fuse.
// - 16 stages x (24 MFMA + 2 A-float4/thread + 8 B-loads/wave + 1 barrier).

#define T_TOKENS 32768
#define D_MODEL  1024
#define NE       64
#define NCOL     128
#define M_TILE   32
#define NSTAGE   (D_MODEL / 64)        // 16 stages of K=64 (2 chunks)
#define CS_LD    68
#define OUT_IDX_BASE ((size_t)T_TOKENS * NE)
#define W_ELEMS  (NCOL * D_MODEL)

typedef short  bf16x8  __attribute__((ext_vector_type(8)));
typedef float  floatx4 __attribute__((ext_vector_type(4)));

__device__ __forceinline__ unsigned short f32_to_bf16_rne(float x) {
    unsigned u = __float_as_uint(x);
    unsigned r = u + 0x7fffu + ((u >> 16) & 1u);
    return (unsigned short)(r >> 16);
}
__device__ __forceinline__ float bf16_bits_to_f32(unsigned short h) {
    return __uint_as_float(((unsigned)h) << 16);
}
__device__ __forceinline__ float softplus_f(float x) {
    return fmaxf(x, 0.f) + log1pf(expf(-fabsf(x)));
}

// ---------------- prepack: W -> hi/lo bf16 in B-frag order ----------------
// elem index = ((ntile*128 + kgrp)*16 + n16)*8 + j ; value = W[ntile*16+n16][kgrp*8+j]
__global__ __launch_bounds__(256) void prepack_w(
    const float* __restrict__ Wr, const float* __restrict__ Wn,
    short* __restrict__ Bh, short* __restrict__ Bl)
{
    int g   = blockIdx.x * 256 + threadIdx.x;
    int n   = g & 15;
    int kg  = (g >> 4) & 127;
    int t2  = g >> 11;
    int col = t2 * 16 + n;
    const float* src = (col < NE ? Wr + (size_t)col * D_MODEL
                                 : Wn + (size_t)(col - NE) * D_MODEL) + kg * 8;
    float4 a = *(const float4*)src;
    float4 b = *(const float4*)(src + 4);
    float v[8] = {a.x, a.y, a.z, a.w, b.x, b.y, b.z, b.w};
    unsigned short h[8], l[8];
    #pragma unroll
    for (int j = 0; j < 8; ++j) {
        h[j] = f32_to_bf16_rne(v[j]);
        l[j] = f32_to_bf16_rne(v[j] - bf16_bits_to_f32(h[j]));
    }
    int4 hp, lp;
    hp.x = (int)((unsigned)h[0] | ((unsigned)h[1] << 16));
    hp.y = (int)((unsigned)h[2] | ((unsigned)h[3] << 16));
    hp.z = (int)((unsigned)h[4] | ((unsigned)h[5] << 16));
    hp.w = (int)((unsigned)h[6] | ((unsigned)h[7] << 16));
    lp.x = (int)((unsigned)l[0] | ((unsigned)l[1] << 16));
    lp.y = (int)((unsigned)l[2] | ((unsigned)l[3] << 16));
    lp.z = (int)((unsigned)l[4] | ((unsigned)l[5] << 16));
    lp.w = (int)((unsigned)l[6] | ((unsigned)l[7] << 16));
    *(int4*)(Bh + (size_t)g * 8) = hp;
    *(int4*)(Bl + (size_t)g * 8) = lp;
}

// ---------------- main fused kernel ----------------
__global__ __launch_bounds__(256, 4) void router_mfma(
    const float* __restrict__ A,
    const float* __restrict__ noise,
    const float* __restrict__ br,
    const float* __restrict__ bn,
    const short* __restrict__ Bh,
    const short* __restrict__ Bl,
    float* __restrict__ out)
{
    // stage buffers: 2 chunks x (32 tokens x 32 k) each, frag order within chunk
    __shared__ __align__(16) short Ah[2][2 * M_TILE * 32];
    __shared__ __align__(16) short Al[2][2 * M_TILE * 32];
    __shared__ float Cs[M_TILE * CS_LD];
    __shared__ float s_p1[M_TILE], s_p2[M_TILE];
    __shared__ int   s_e1[M_TILE], s_e2[M_TILE];

    const int tid  = threadIdx.x;
    const int lane = tid & 63;
    const int wid  = tid >> 6;
    const int n16  = lane & 15;
    const int quad = lane >> 4;
    const int m0   = blockIdx.x * M_TILE;

    // staging mapping: tid -> (token ms, float4 kq within chunk)
    const int ms = tid >> 3;          // 0..31
    const int kq = tid & 7;           // 0..7
    const float* pA = A + (size_t)(m0 + ms) * D_MODEL + kq * 4;
    const int sBase = ((kq >> 1) * M_TILE + ms) * 8 + (kq & 1) * 4;

    const int bBaseR = ((wid * 128 + quad) * 16 + n16) * 8;
    const int bBaseN = (((4 + wid) * 128 + quad) * 16 + n16) * 8;

    floatx4 acc[2][2];
    #pragma unroll
    for (int i = 0; i < 2; ++i) { acc[i][0] = (floatx4)0.f; acc[i][1] = (floatx4)0.f; }

#define CONVERT_STORE(buf_, c_, f4_) do {                                    \
        float v_[4] = {(f4_).x, (f4_).y, (f4_).z, (f4_).w};                  \
        unsigned short h_[4], l_[4];                                         \
        _Pragma("unroll")                                                    \
        for (int j_ = 0; j_ < 4; ++j_) {                                     \
            h_[j_] = f32_to_bf16_rne(v_[j_]);                                \
            l_[j_] = f32_to_bf16_rne(v_[j_] - bf16_bits_to_f32(h_[j_]));     \
        }                                                                    \
        int2 hp_, lp_;                                                       \
        hp_.x = (int)((unsigned)h_[0] | ((unsigned)h_[1] << 16));            \
        hp_.y = (int)((unsigned)h_[2] | ((unsigned)h_[3] << 16));            \
        lp_.x = (int)((unsigned)l_[0] | ((unsigned)l_[1] << 16));            \
        lp_.y = (int)((unsigned)l_[2] | ((unsigned)l_[3] << 16));            \
        *(int2*)&Ah[(buf_)][(c_) * (M_TILE * 32) + sBase] = hp_;             \
        *(int2*)&Al[(buf_)][(c_) * (M_TILE * 32) + sBase] = lp_;             \
    } while (0)

    // ---- prologue: stage 0 into buf0; raw pipeline holds stages 1,2 ----
    {
        float4 s0c0 = *(const float4*)(pA);
        float4 s0c1 = *(const float4*)(pA + 32);
        CONVERT_STORE(0, 0, s0c0);
        CONVERT_STORE(0, 1, s0c1);
    }
    float4 aP1[2], aP2[2];
    aP1[0] = *(const float4*)(pA + 64);
    aP1[1] = *(const float4*)(pA + 96);
    aP2[0] = *(const float4*)(pA + 128);
    aP2[1] = *(const float4*)(pA + 160);
    __syncthreads();

    for (int ks = 0; ks < NSTAGE; ++ks) {
        const int cur = ks & 1, nxt = cur ^ 1;

        // B loads for chunks 2ks, 2ks+1 (consumed after convert block)
        bf16x8 bhR[2], blR[2], bhN[2], blN[2];
        #pragma unroll
        for (int c = 0; c < 2; ++c) {
            int o = (2 * ks + c) * 512;
            bhR[c] = *(const bf16x8*)(Bh + bBaseR + o);
            blR[c] = *(const bf16x8*)(Bl + bBaseR + o);
            bhN[c] = *(const bf16x8*)(Bh + bBaseN + o);
            blN[c] = *(const bf16x8*)(Bl + bBaseN + o);
        }

        // raw A for stage ks+3 (longest latency, deepest slack)
        float4 aP3[2];
        if (ks + 3 < NSTAGE) {
            aP3[0] = *(const float4*)(pA + (ks + 3) * 64);
            aP3[1] = *(const float4*)(pA + (ks + 3) * 64 + 32);
        }

        // A frags for both chunks of this stage
        bf16x8 afh[2][2], afl[2][2];
        #pragma unroll
        for (int c = 0; c < 2; ++c)
            #pragma unroll
            for (int mf = 0; mf < 2; ++mf) {
                int g = c * (M_TILE * 32) + (quad * M_TILE + mf * 16 + n16) * 8;
                afh[c][mf] = *(const bf16x8*)&Ah[cur][g];
                afl[c][mf] = *(const bf16x8*)&Al[cur][g];
            }

        // convert + stage ks+1 (raw loaded 2 iterations ago; VALU fills B latency)
        if (ks + 1 < NSTAGE) {
            CONVERT_STORE(nxt, 0, aP1[0]);
            CONVERT_STORE(nxt, 1, aP1[1]);
        }

        // 24 MFMAs
        #pragma unroll
        for (int c = 0; c < 2; ++c)
            #pragma unroll
            for (int mf = 0; mf < 2; ++mf) {
                acc[mf][0] = __builtin_amdgcn_mfma_f32_16x16x32_bf16(afh[c][mf], bhR[c], acc[mf][0], 0, 0, 0);
                acc[mf][0] = __builtin_amdgcn_mfma_f32_16x16x32_bf16(afh[c][mf], blR[c], acc[mf][0], 0, 0, 0);
                acc[mf][0] = __builtin_amdgcn_mfma_f32_16x16x32_bf16(afl[c][mf], bhR[c], acc[mf][0], 0, 0, 0);
                acc[mf][1] = __builtin_amdgcn_mfma_f32_16x16x32_bf16(afh[c][mf], bhN[c], acc[mf][1], 0, 0, 0);
                acc[mf][1] = __builtin_amdgcn_mfma_f32_16x16x32_bf16(afh[c][mf], blN[c], acc[mf][1], 0, 0, 0);
                acc[mf][1] = __builtin_amdgcn_mfma_f32_16x16x32_bf16(afl[c][mf], bhN[c], acc[mf][1], 0, 0, 0);
            }

        __syncthreads();

        // rotate raw-A pipeline
        aP1[0] = aP2[0]; aP1[1] = aP2[1];
        aP2[0] = aP3[0]; aP2[1] = aP3[1];
    }

    // ---- lane-local fuse: noisy = route + noise * softplus(noise_logit) ----
    {
        int e = wid * 16 + n16;
        float brv = br[e], bnv = bn[e];
        #pragma unroll
        for (int mf = 0; mf < 2; ++mf)
            #pragma unroll
            for (int r = 0; r < 4; ++r) {
                int t = mf * 16 + quad * 4 + r;
                float nz    = noise[(size_t)(m0 + t) * NE + e];
                float route = acc[mf][0][r] + brv;
                float nl    = acc[mf][1][r] + bnv;
                Cs[t * CS_LD + e] = fmaf(nz, softplus_f(nl), route);
            }
    }
    __syncthreads();

    // ---- top-2 + softmax (one thread per token; in-order scan = stable ties) ----
    if (tid < M_TILE) {
        const int t = tid;
        float v1 = -INFINITY, v2 = -INFINITY;
        int e1 = 0, e2 = 0;
        #pragma unroll 8
        for (int e = 0; e < NE; ++e) {
            float v = Cs[t * CS_LD + e];
            if (v > v1) { v2 = v1; e2 = e1; v1 = v; e1 = e; }
            else if (v > v2) { v2 = v; e2 = e; }
        }
        float ex = expf(v2 - v1);
        float denom = 1.f + ex;
        s_p1[t] = 1.f / denom;
        s_p2[t] = ex / denom;
        s_e1[t] = e1;
        s_e2[t] = e2;
        float2 iv = make_float2((float)e1, (float)e2);
        *(float2*)(out + OUT_IDX_BASE + (size_t)(m0 + t) * 2) = iv;
    }
    __syncthreads();

    // ---- coalesced scatter of router_output [32 tokens x 64 experts] ----
    #pragma unroll
    for (int i = 0; i < 2; ++i) {
        int gi = i * 256 + tid;
        int t  = gi >> 4;
        int e0 = (gi & 15) * 4;
        float p1 = s_p1[t], p2 = s_p2[t];
        int   e1 = s_e1[t], e2 = s_e2[t];
        float4 v;
        v.x = (e0 + 0 == e1) ? p1 : ((e0 + 0 == e2) ? p2 : 0.f);
        v.y = (e0 + 1 == e1) ? p1 : ((e0 + 1 == e2) ? p2 : 0.f);
        v.z = (e0 + 2 == e1) ? p1 : ((e0 + 2 == e2) ? p2 : 0.f);
        v.w = (e0 + 3 == e1) ? p1 : ((e0 + 3 == e2) ? p2 : 0.f);
        *(float4*)(out + (size_t)(m0 + t) * NE + e0) = v;
    }
}

extern "C" void kernel_launch(void* const* d_in, const int* in_sizes, int n_in,
                              void* d_out, int out_size, void* d_ws, size_t ws_size,
                              hipStream_t stream) {
    const float* A     = (const float*)d_in[0];
    const float* noise = (const float*)d_in[1];
    const float* Wr    = (const float*)d_in[2];
    const float* br    = (const float*)d_in[3];
    const float* Wn    = (const float*)d_in[4];
    const float* bn    = (const float*)d_in[5];
    float* out = (float*)d_out;

    short* Bh = (short*)d_ws;
    short* Bl = Bh + W_ELEMS;

    prepack_w<<<dim3(W_ELEMS / 8 / 256), dim3(256), 0, stream>>>(Wr, Wn, Bh, Bl);
    router_mfma<<<dim3(T_TOKENS / M_TILE), dim3(256), 0, stream>>>(A, noise, br, bn, Bh, Bl, out);
}

// Round 6
// 229.268 us; speedup vs baseline: 1.0172x; 1.0172x over previous
//
#include <hip/hip_runtime.h>
#include <hip/hip_bf16.h>
#include <math.h>

// NoisyTopkRouter round 6: bf16x2-split MFMA, M=64 per wave.
// - Each of 4 waves computes ALL 64 rows x its (route ntile w, noise ntile w+4)
//   -> B-fragment VMEM instructions halve vs r4/r5 (theory: per-CU VMEM
//   wave-instruction throughput is the binding resource).
// - Cheap fp32->bf16 hi/lo: __float22bfloat162_rn pair + exact hi via bit mask.
// - 1 barrier/chunk, B register-prefetch 1 chunk ahead, raw-A depth 2 iters.

#define T_TOKENS 32768
#define D_MODEL  1024
#define NE       64
#define NCOL     128
#define M_TILE   64
#define NCHUNK   32
#define CS_LD    68
#define OUT_IDX_BASE ((size_t)T_TOKENS * NE)
#define W_ELEMS  (NCOL * D_MODEL)

typedef short  bf16x8  __attribute__((ext_vector_type(8)));
typedef float  floatx4 __attribute__((ext_vector_type(4)));

__device__ __forceinline__ float softplus_f(float x) {
    return fmaxf(x, 0.f) + log1pf(expf(-fabsf(x)));
}

// 8 floats -> packed bf16 hi (int4) + bf16 lo (int4). RNE hi, exact residual,
// RNE lo — numerically identical to rounds 2-5.
__device__ __forceinline__ void cvt8(const float4 a, const float4 b,
                                     int4* hi, int4* lo) {
    float v[8] = {a.x, a.y, a.z, a.w, b.x, b.y, b.z, b.w};
    int hw[4], lw[4];
    #pragma unroll
    for (int p = 0; p < 4; ++p) {
        float2 f2 = make_float2(v[2 * p], v[2 * p + 1]);
        __hip_bfloat162 h2 = __float22bfloat162_rn(f2);
        int u; __builtin_memcpy(&u, &h2, 4);
        float h0 = __uint_as_float(((unsigned)u) << 16);
        float h1 = __uint_as_float(((unsigned)u) & 0xFFFF0000u);
        float2 l2 = make_float2(v[2 * p] - h0, v[2 * p + 1] - h1);
        __hip_bfloat162 L2 = __float22bfloat162_rn(l2);
        int ul; __builtin_memcpy(&ul, &L2, 4);
        hw[p] = u; lw[p] = ul;
    }
    *hi = make_int4(hw[0], hw[1], hw[2], hw[3]);
    *lo = make_int4(lw[0], lw[1], lw[2], lw[3]);
}

// ---------------- prepack: W -> hi/lo bf16 in B-frag order ----------------
// elem index = ((ntile*128 + kgrp)*16 + n16)*8 + j ; value = W[ntile*16+n16][kgrp*8+j]
__global__ __launch_bounds__(256) void prepack_w(
    const float* __restrict__ Wr, const float* __restrict__ Wn,
    short* __restrict__ Bh, short* __restrict__ Bl)
{
    int g   = blockIdx.x * 256 + threadIdx.x;
    int n   = g & 15;
    int kg  = (g >> 4) & 127;
    int t2  = g >> 11;
    int col = t2 * 16 + n;
    const float* src = (col < NE ? Wr + (size_t)col * D_MODEL
                                 : Wn + (size_t)(col - NE) * D_MODEL) + kg * 8;
    float4 a = *(const float4*)src;
    float4 b = *(const float4*)(src + 4);
    int4 hi, lo;
    cvt8(a, b, &hi, &lo);
    *(int4*)(Bh + (size_t)g * 8) = hi;
    *(int4*)(Bl + (size_t)g * 8) = lo;
}

// ---------------- main fused kernel ----------------
__global__ __launch_bounds__(256, 2) void router_mfma(
    const float* __restrict__ A,
    const float* __restrict__ noise,
    const float* __restrict__ br,
    const float* __restrict__ bn,
    const short* __restrict__ Bh,
    const short* __restrict__ Bl,
    float* __restrict__ out)
{
    __shared__ __align__(16) short Ah[2][M_TILE * 32];
    __shared__ __align__(16) short Al[2][M_TILE * 32];
    __shared__ float Cs[M_TILE * CS_LD];
    __shared__ float s_p1[M_TILE], s_p2[M_TILE];
    __shared__ int   s_e1[M_TILE], s_e2[M_TILE];

    const int tid  = threadIdx.x;
    const int lane = tid & 63;
    const int wid  = tid >> 6;   // wave: route ntile wid, noise ntile wid+4
    const int n16  = lane & 15;
    const int quad = lane >> 4;
    const int m0   = blockIdx.x * M_TILE;

    // staging: row r = tid&63, k-half kh = tid>>6 -> k = kh*8..kh*8+7 (32B/thread)
    const int r  = tid & 63;
    const int kh = tid >> 6;
    const float* pA = A + (size_t)(m0 + r) * D_MODEL + kh * 8;
    const int sBase = (kh * M_TILE + r) * 8;   // frag-order elem base, 16B aligned

    const int bBaseR = ((wid * 128 + quad) * 16 + n16) * 8;
    const int bBaseN = (((4 + wid) * 128 + quad) * 16 + n16) * 8;

    floatx4 acc[4][2];
    #pragma unroll
    for (int i = 0; i < 4; ++i) { acc[i][0] = (floatx4)0.f; acc[i][1] = (floatx4)0.f; }

    // ---- prologue: stage chunk 0; B(0) into regs; raw A for chunks 1,2 ----
    {
        float4 a0 = *(const float4*)pA;
        float4 a1 = *(const float4*)(pA + 4);
        int4 hi, lo;
        cvt8(a0, a1, &hi, &lo);
        *(int4*)&Ah[0][sBase] = hi;
        *(int4*)&Al[0][sBase] = lo;
    }
    bf16x8 bhR, blR, bhN, blN;
    bhR = *(const bf16x8*)(Bh + bBaseR);
    blR = *(const bf16x8*)(Bl + bBaseR);
    bhN = *(const bf16x8*)(Bh + bBaseN);
    blN = *(const bf16x8*)(Bl + bBaseN);
    float4 aP1a = *(const float4*)(pA + 32), aP1b = *(const float4*)(pA + 36);
    float4 aP2a = *(const float4*)(pA + 64), aP2b = *(const float4*)(pA + 68);
    __syncthreads();

    for (int kc = 0; kc < NCHUNK; ++kc) {
        const int cur = kc & 1, nxt = cur ^ 1;

        // raw A for chunk kc+3 (deepest slack)
        float4 f0, f1;
        if (kc + 3 < NCHUNK) {
            f0 = *(const float4*)(pA + (kc + 3) * 32);
            f1 = *(const float4*)(pA + (kc + 3) * 32 + 4);
        }
        // B for chunk kc+1
        bf16x8 bhRn, blRn, bhNn, blNn;
        if (kc + 1 < NCHUNK) {
            int o = (kc + 1) * 512;
            bhRn = *(const bf16x8*)(Bh + bBaseR + o);
            blRn = *(const bf16x8*)(Bl + bBaseR + o);
            bhNn = *(const bf16x8*)(Bh + bBaseN + o);
            blNn = *(const bf16x8*)(Bl + bBaseN + o);
        }

        // A frags (4 m-frags, conflict pattern same as proven rounds)
        bf16x8 afh[4], afl[4];
        #pragma unroll
        for (int mf = 0; mf < 4; ++mf) {
            int g = (quad * M_TILE + mf * 16 + n16) * 8;
            afh[mf] = *(const bf16x8*)&Ah[cur][g];
            afl[mf] = *(const bf16x8*)&Al[cur][g];
        }

        // convert + stage chunk kc+1 (raw loaded 2 iterations ago)
        if (kc + 1 < NCHUNK) {
            int4 hi, lo;
            cvt8(aP1a, aP1b, &hi, &lo);
            *(int4*)&Ah[nxt][sBase] = hi;
            *(int4*)&Al[nxt][sBase] = lo;
        }

        // 24 MFMAs (8 independent acc chains, depth 3)
        #pragma unroll
        for (int mf = 0; mf < 4; ++mf) {
            acc[mf][0] = __builtin_amdgcn_mfma_f32_16x16x32_bf16(afh[mf], bhR, acc[mf][0], 0, 0, 0);
            acc[mf][0] = __builtin_amdgcn_mfma_f32_16x16x32_bf16(afh[mf], blR, acc[mf][0], 0, 0, 0);
            acc[mf][0] = __builtin_amdgcn_mfma_f32_16x16x32_bf16(afl[mf], bhR, acc[mf][0], 0, 0, 0);
            acc[mf][1] = __builtin_amdgcn_mfma_f32_16x16x32_bf16(afh[mf], bhN, acc[mf][1], 0, 0, 0);
            acc[mf][1] = __builtin_amdgcn_mfma_f32_16x16x32_bf16(afh[mf], blN, acc[mf][1], 0, 0, 0);
            acc[mf][1] = __builtin_amdgcn_mfma_f32_16x16x32_bf16(afl[mf], blN == blN ? bhN : bhN, acc[mf][1], 0, 0, 0);
        }

        __syncthreads();

        aP1a = aP2a; aP1b = aP2b; aP2a = f0; aP2b = f1;
        bhR = bhRn; blR = blRn; bhN = bhNn; blN = blNn;
    }

    // ---- lane-local fuse: noisy = route + noise * softplus(noise_logit) ----
    // D layout: col = lane&15, row = quad*4 + r
    {
        int e = wid * 16 + n16;
        float brv = br[e], bnv = bn[e];
        #pragma unroll
        for (int mf = 0; mf < 4; ++mf)
            #pragma unroll
            for (int rr = 0; rr < 4; ++rr) {
                int t = mf * 16 + quad * 4 + rr;
                float nz    = noise[(size_t)(m0 + t) * NE + e];
                float route = acc[mf][0][rr] + brv;
                float nl    = acc[mf][1][rr] + bnv;
                Cs[t * CS_LD + e] = fmaf(nz, softplus_f(nl), route);
            }
    }
    __syncthreads();

    // ---- top-2 + softmax (one thread per token; in-order scan = stable ties) ----
    if (tid < M_TILE) {
        const int t = tid;
        float v1 = -INFINITY, v2 = -INFINITY;
        int e1 = 0, e2 = 0;
        #pragma unroll
        for (int e4 = 0; e4 < 16; ++e4) {
            float4 q = *(const float4*)&Cs[t * CS_LD + e4 * 4];
            float qa[4] = {q.x, q.y, q.z, q.w};
            #pragma unroll
            for (int c = 0; c < 4; ++c) {
                float v = qa[c];
                int e = e4 * 4 + c;
                if (v > v1) { v2 = v1; e2 = e1; v1 = v; e1 = e; }
                else if (v > v2) { v2 = v; e2 = e; }
            }
        }
        float ex = expf(v2 - v1);
        float denom = 1.f + ex;
        s_p1[t] = 1.f / denom;
        s_p2[t] = ex / denom;
        s_e1[t] = e1;
        s_e2[t] = e2;
        float2 iv = make_float2((float)e1, (float)e2);
        *(float2*)(out + OUT_IDX_BASE + (size_t)(m0 + t) * 2) = iv;
    }
    __syncthreads();

    // ---- coalesced scatter of router_output [64 tokens x 64 experts] ----
    #pragma unroll
    for (int i = 0; i < 4; ++i) {
        int gi = i * 256 + tid;       // 0..1023 float4s
        int t  = gi >> 4;
        int e0 = (gi & 15) * 4;
        float p1 = s_p1[t], p2 = s_p2[t];
        int   e1 = s_e1[t], e2 = s_e2[t];
        float4 v;
        v.x = (e0 + 0 == e1) ? p1 : ((e0 + 0 == e2) ? p2 : 0.f);
        v.y = (e0 + 1 == e1) ? p1 : ((e0 + 1 == e2) ? p2 : 0.f);
        v.z = (e0 + 2 == e1) ? p1 : ((e0 + 2 == e2) ? p2 : 0.f);
        v.w = (e0 + 3 == e1) ? p1 : ((e0 + 3 == e2) ? p2 : 0.f);
        *(float4*)(out + (size_t)(m0 + t) * NE + e0) = v;
    }
}

extern "C" void kernel_launch(void* const* d_in, const int* in_sizes, int n_in,
                              void* d_out, int out_size, void* d_ws, size_t ws_size,
                              hipStream_t stream) {
    const float* A     = (const float*)d_in[0];
    const float* noise = (const float*)d_in[1];
    const float* Wr    = (const float*)d_in[2];
    const float* br    = (const float*)d_in[3];
    const float* Wn    = (const float*)d_in[4];
    const float* bn    = (const float*)d_in[5];
    float* out = (float*)d_out;

    short* Bh = (short*)d_ws;
    short* Bl = Bh + W_ELEMS;

    prepack_w<<<dim3(W_ELEMS / 8 / 256), dim3(256), 0, stream>>>(Wr, Wn, Bh, Bl);
    router_mfma<<<dim3(T_TOKENS / M_TILE), dim3(256), 0, stream>>>(A, noise, br, bn, Bh, Bl, out);
}